// Round 5
// baseline (351.736 us; speedup 1.0000x reference)
//
#include <hip/hip_runtime.h>
#include <math.h>

// ---------------- problem constants ----------------
#define GG   16      // stripes
#define KK   4       // latents per stripe
#define NN   64      // batch
#define CC   256     // channels
#define SHH  4       // stripe height
#define WW   44      // width
#define PP   176     // pixels per stripe
#define HWSZ 2816    // 64*44
#define CHW  720896  // CC*HWSZ
#define TOPKK 22     // int(176*0.125)

// ---------------- DPP wave64 ops (VALU pipe) ----------------
template<int CTRL, int RMASK>
__device__ __forceinline__ float dpp0(float v) {
    return __int_as_float(__builtin_amdgcn_update_dpp(
        0, __float_as_int(v), CTRL, RMASK, 0xF, true));
}
__device__ __forceinline__ float nbrL(float v) { return dpp0<0x138, 0xF>(v); } // wave_shr1
__device__ __forceinline__ float nbrR(float v) { return dpp0<0x130, 0xF>(v); } // wave_shl1

// sum of all 64 lanes; result valid on lane 63 only
__device__ __forceinline__ float wave_sum63(float v) {
    v += dpp0<0x111, 0xF>(v);
    v += dpp0<0x112, 0xF>(v);
    v += dpp0<0x114, 0xF>(v);
    v += dpp0<0x118, 0xF>(v);
    v += dpp0<0x142, 0xA>(v);   // bcast15 into rows 1,3
    v += dpp0<0x143, 0xC>(v);   // bcast31 into rows 2,3
    return v;
}
__device__ __forceinline__ float bcast63(float v) {
    return __int_as_float(__builtin_amdgcn_readlane(__float_as_int(v), 63));
}
__device__ __forceinline__ float wave_sum_all(float v) { return bcast63(wave_sum63(v)); }

// max over 64 lanes, broadcast; requires true max >= 0 (zero-fill safe)
__device__ __forceinline__ float wave_max_nn(float v) {
    v = fmaxf(v, dpp0<0x111, 0xF>(v));
    v = fmaxf(v, dpp0<0x112, 0xF>(v));
    v = fmaxf(v, dpp0<0x114, 0xF>(v));
    v = fmaxf(v, dpp0<0x118, 0xF>(v));
    v = fmaxf(v, dpp0<0x142, 0xA>(v));
    v = fmaxf(v, dpp0<0x143, 0xC>(v));
    return bcast63(v);
}

// ---------------- routing kernel (basis-norm folded in) ----------------
// grid (GG, NN), 512 threads = 8 waves; wave w owns channels [w*32, w*32+32).
// Register 3x3 pooling via DPP, prefetch depth 2; one LDS cross-wave
// reduction; finalize + topk; sup/pw to small ws for tokscat.
__global__ __launch_bounds__(512, 8) void routing_kernel(
    const float* __restrict__ x, const float* __restrict__ lb_raw,
    float* __restrict__ sup_ws, float* __restrict__ pw_ws,
    float* __restrict__ pres_ws) {
    const int g = blockIdx.x;
    const int n = blockIdx.y;
    const int tid = threadIdx.x;
    const int w = __builtin_amdgcn_readfirstlane(tid >> 6);
    const int lane = tid & 63;
    const bool al = lane < WW;

    __shared__ float4 pd[8][PP];     // per-wave d partials; pd[0] -> sum
    __shared__ float2 pnf[8][PP];    // (nrm, fe) partials; pnf[0] -> sum
    __shared__ float4 lbn_lds[CC];   // [c] -> float4 over k, scaled by 1/9
    __shared__ float redA[4], redB[4], zred[4][4];
    float4* sup4 = pd[2];            // reused after reduction
    float4* pw4  = pd[4];

    // ---- basis norm: wave k (0..3) normalizes latent (g,k) into LDS ----
    if (w < 4) {
        const float* row = lb_raw + ((size_t)g * KK + w) * CC;
        float v0 = row[lane], v1 = row[lane + 64], v2 = row[lane + 128], v3 = row[lane + 192];
        float ss = v0 * v0 + v1 * v1 + v2 * v2 + v3 * v3;
        float tot = wave_sum_all(ss);
        float sc = (1.0f / 9.0f) / fmaxf(sqrtf(tot), 1e-12f);
        float* dst = (float*)lbn_lds;
        dst[lane * 4 + w]         = v0 * sc;
        dst[(lane + 64) * 4 + w]  = v1 * sc;
        dst[(lane + 128) * 4 + w] = v2 * sc;
        dst[(lane + 192) * 4 + w] = v3 * sc;
    }
    __syncthreads();

    const float* xb = x + (size_t)n * CHW + g * PP;
    const int c0 = w * 32;

    float4 dk[4];
    float nr[4] = {0, 0, 0, 0}, fe[4] = {0, 0, 0, 0};
    #pragma unroll
    for (int s = 0; s < 4; ++s) dk[s] = make_float4(0, 0, 0, 0);

    // prefetch depth 2: channels i (cur), i+1 (nx) in flight
    const float* xp = xb + (size_t)c0 * HWSZ + lane;
    float c0r = 0, c1r = 0, c2r = 0, c3r = 0;
    float n0r = 0, n1r = 0, n2r = 0, n3r = 0;
    if (al) {
        c0r = xp[0]; c1r = xp[44]; c2r = xp[88]; c3r = xp[132];
        n0r = xp[HWSZ]; n1r = xp[HWSZ + 44]; n2r = xp[HWSZ + 88]; n3r = xp[HWSZ + 132];
    }
    xp += 2 * HWSZ;
    #pragma unroll 1
    for (int i = 0; i < 32; ++i) {
        float f0 = 0, f1 = 0, f2 = 0, f3 = 0;
        if (i < 30 && al) { f0 = xp[0]; f1 = xp[44]; f2 = xp[88]; f3 = xp[132]; }
        xp += HWSZ;
        float4 lbv = lbn_lds[c0 + i];   // wave-uniform -> LDS broadcast
        fe[0] += c0r * c0r; fe[1] += c1r * c1r; fe[2] += c2r * c2r; fe[3] += c3r * c3r;
        float h0 = c0r + nbrL(c0r) + nbrR(c0r);
        float h1 = c1r + nbrL(c1r) + nbrR(c1r);
        float h2 = c2r + nbrL(c2r) + nbrR(c2r);
        float h3 = c3r + nbrL(c3r) + nbrR(c3r);
        // raw 3x3 sums (1/9 folded into lbv; nrm fixed via inv=72/sqrt)
        float p0 = h0 + h1;          // row -1 zero pad
        float p1 = p0 + h2;
        float t23 = h2 + h3;
        float p2 = h1 + t23;
        float p3 = t23;              // row 4 zero pad
        nr[0] += p0 * p0; nr[1] += p1 * p1; nr[2] += p2 * p2; nr[3] += p3 * p3;
        dk[0].x += p0 * lbv.x; dk[0].y += p0 * lbv.y; dk[0].z += p0 * lbv.z; dk[0].w += p0 * lbv.w;
        dk[1].x += p1 * lbv.x; dk[1].y += p1 * lbv.y; dk[1].z += p1 * lbv.z; dk[1].w += p1 * lbv.w;
        dk[2].x += p2 * lbv.x; dk[2].y += p2 * lbv.y; dk[2].z += p2 * lbv.z; dk[2].w += p2 * lbv.w;
        dk[3].x += p3 * lbv.x; dk[3].y += p3 * lbv.y; dk[3].z += p3 * lbv.z; dk[3].w += p3 * lbv.w;
        c0r = n0r; c1r = n1r; c2r = n2r; c3r = n3r;
        n0r = f0; n1r = f1; n2r = f2; n3r = f3;
    }
    if (al) {
        #pragma unroll
        for (int s = 0; s < 4; ++s) {
            pd[w][s * 44 + lane]  = dk[s];
            pnf[w][s * 44 + lane] = make_float2(nr[s], fe[s]);
        }
    }
    __syncthreads();

    // ---- cross-wave reduction into slot 0 ----
    if (tid < PP) {
        float4 a = pd[0][tid];
        #pragma unroll
        for (int ww = 1; ww < 8; ++ww) {
            float4 b = pd[ww][tid];
            a.x += b.x; a.y += b.y; a.z += b.z; a.w += b.w;
        }
        pd[0][tid] = a;
    } else if (tid >= 256 && tid < 256 + PP) {
        const int p = tid - 256;
        float2 a = pnf[0][p];
        #pragma unroll
        for (int ww = 1; ww < 8; ++ww) {
            float2 b = pnf[ww][p];
            a.x += b.x; a.y += b.y;
        }
        pnf[0][p] = a;
    }
    __syncthreads();

    // ---- finalize (8 waves redundant; waves 0..3 write) ----
    const int s4 = w & 3;
    const int pix = s4 * 44 + (al ? lane : 0);
    float4 dv = pd[0][pix];
    float2 nf = pnf[0][pix];
    float nrm = nf.x;
    float fev = nf.y * (1.0f / 256.0f);

    float fmw = wave_max_nn(al ? fev : 0.0f);
    if (w < 4 && lane == 0) redA[s4] = fmw;
    __syncthreads();
    float femax = fmaxf(fmaxf(redA[0], redA[1]), fmaxf(redA[2], redA[3]));
    float den = fmaxf(femax, 1e-6f);
    bool pa = al && ((fev / den) > 0.05f);
    unsigned long long bl = __ballot((int)pa);
    if (w < 4 && lane == 0) redB[s4] = (float)__popcll(bl);
    __syncthreads();
    float cnt = redB[0] + redB[1] + redB[2] + redB[3];
    float actv = pa ? 1.0f : 0.0f;
    if (cnt <= 0.0f) actv = (al && (fev > 0.0f)) ? 1.0f : 0.0f;

    float inv = 72.0f / fmaxf(sqrtf(nrm), 9e-12f);   // 8/TEMP on raw 3x3 sums
    float L0 = dv.x * inv, L1 = dv.y * inv, L2 = dv.z * inv, L3 = dv.w * inv;
    float mx = fmaxf(fmaxf(L0, L1), fmaxf(L2, L3));
    float e0 = expf(L0 - mx), e1 = expf(L1 - mx), e2 = expf(L2 - mx), e3 = expf(L3 - mx);
    float esum = e0 + e1 + e2 + e3;
    float sc = actv / esum;
    float s0 = e0 * sc, s1 = e1 * sc, s2 = e2 * sc, s3 = e3 * sc;

    float z0 = wave_sum63(s0), z1 = wave_sum63(s1), z2 = wave_sum63(s2), z3 = wave_sum63(s3);
    if (w < 4 && lane == 63) { zred[s4][0] = z0; zred[s4][1] = z1; zred[s4][2] = z2; zred[s4][3] = z3; }
    __syncthreads();
    float Z0 = zred[0][0] + zred[1][0] + zred[2][0] + zred[3][0];
    float Z1 = zred[0][1] + zred[1][1] + zred[2][1] + zred[3][1];
    float Z2 = zred[0][2] + zred[1][2] + zred[2][2] + zred[3][2];
    float Z3 = zred[0][3] + zred[1][3] + zred[2][3] + zred[3][3];
    float q0 = s0 / fmaxf(Z0, 1e-6f);
    float q1 = s1 / fmaxf(Z1, 1e-6f);
    float q2 = s2 / fmaxf(Z2, 1e-6f);
    float q3 = s3 / fmaxf(Z3, 1e-6f);

    if (w < 4 && al) {
        float4 sv = make_float4(s0, s1, s2, s3);
        float4 qv = make_float4(q0, q1, q2, q3);
        sup4[pix] = sv;
        pw4[pix]  = qv;
        const size_t wsb = (size_t)(n * GG + g) * PP + pix;
        ((float4*)sup_ws)[wsb] = sv;
        ((float4*)pw_ws)[wsb]  = qv;
    }
    __syncthreads();

    // ---- top-22 presence: wave k (0..3) ----
    if (w < 4) {
        const float* supf = (const float*)sup4;
        const int k = w;
        float v0 = supf[lane * 4 + k];
        float v1 = supf[(lane + 64) * 4 + k];
        float v2 = (lane < PP - 128) ? supf[(lane + 128) * 4 + k] : -1e30f;
        float tks = 0.0f;
        for (int it = 0; it < TOPKK; ++it) {
            float lm = fmaxf(v0, fmaxf(v1, v2));
            float M = wave_max_nn(lm);
            tks += M;
            unsigned long long mk = __ballot((int)(lm == M));
            int src = __ffsll(mk) - 1;
            if (lane == src) {
                if (v0 == M)      v0 = -1e30f;
                else if (v1 == M) v1 = -1e30f;
                else              v2 = -1e30f;
            }
        }
        if (lane == 0) pres_ws[(size_t)n * 64 + g * KK + k] = tks * (1.0f / (float)TOPKK);
    }
}

// ---------------- merged token + scatter kernel ----------------
// grid (GG, NN), 512 threads = 8 waves. Scatter is write-drain-bound,
// token is read-latency-bound -> overlap in one block.
__global__ __launch_bounds__(512, 8) void tokscat_kernel(
    const float* __restrict__ x,
    const float4* __restrict__ sup_ws4, const float4* __restrict__ pw_ws4,
    float* __restrict__ tok_out, float4* __restrict__ outS, float4* __restrict__ outP) {
    const int g = blockIdx.x;
    const int n = blockIdx.y;
    const int tid = threadIdx.x;
    const int w = __builtin_amdgcn_readfirstlane(tid >> 6);
    const int lane = tid & 63;

    __shared__ float4 ls[PP], lp[PP];
    const size_t wsb = (size_t)(n * GG + g) * PP;
    if (tid < PP) ls[tid] = sup_ws4[wsb + tid];
    else if (tid >= 256 && tid < 256 + PP) lp[tid - 256] = pw_ws4[wsb + tid - 256];
    __syncthreads();

    // ---- scatter: block owns output pixels [g*176, g*176+176), all 16 quads ----
    {
        const size_t obase = ((size_t)n * HWSZ + (size_t)g * PP) * 16;
        const float4 z = make_float4(0, 0, 0, 0);
        #pragma unroll 1
        for (int j = tid; j < PP * 16; j += 512) {
            const int px = j >> 4, q = j & 15;
            const bool hit = (q == g);
            outS[obase + j] = hit ? ls[px] : z;
            outP[obase + j] = hit ? lp[px] : z;
        }
    }

    // ---- tokens: wave w handles channels [w*32, w*32+32); x re-read L3-hot ----
    {
        float4 pwa = lp[lane];
        float4 pwb = lp[lane + 64];
        float4 pwc = (lane < 48) ? lp[lane + 128] : make_float4(0, 0, 0, 0);
        const int cb = w * 32;
        const float* xp = x + (size_t)n * CHW + g * PP + (size_t)cb * HWSZ + lane;
        float* tokg = tok_out + (size_t)n * CC * 64 + g * KK + (size_t)cb * 64;

        float a0 = xp[0];
        float a1 = xp[64];
        float a2 = (lane < 48) ? xp[128] : 0.0f;
        xp += HWSZ;
        #pragma unroll 1
        for (int i = 0; i < 32; ++i) {
            float b0 = 0, b1 = 0, b2 = 0;
            if (i < 31) {
                b0 = xp[0]; b1 = xp[64];
                if (lane < 48) b2 = xp[128];
            }
            xp += HWSZ;
            float t0 = a0 * pwa.x + a1 * pwb.x + a2 * pwc.x;
            float t1 = a0 * pwa.y + a1 * pwb.y + a2 * pwc.y;
            float t2 = a0 * pwa.z + a1 * pwb.z + a2 * pwc.z;
            float t3 = a0 * pwa.w + a1 * pwb.w + a2 * pwc.w;
            t0 = wave_sum63(t0); t1 = wave_sum63(t1); t2 = wave_sum63(t2); t3 = wave_sum63(t3);
            if (lane == 63) {
                *(float4*)(tokg + (size_t)i * 64) = make_float4(t0, t1, t2, t3);
            }
            a0 = b0; a1 = b1; a2 = b2;
        }
    }
}

// ---------------- presence normalization ----------------
__global__ __launch_bounds__(64) void presence_kernel(
    const float* __restrict__ pres_ws, float* __restrict__ outp) {
    const int n = blockIdx.x;
    const int lane = threadIdx.x;
    float v = pres_ws[(size_t)n * 64 + lane];
    float tot = wave_sum_all(v);
    outp[(size_t)n * 64 + lane] = v / fmaxf(tot, 1e-6f);
}

// ---------------- launch ----------------
extern "C" void kernel_launch(void* const* d_in, const int* in_sizes, int n_in,
                              void* d_out, int out_size, void* d_ws, size_t ws_size,
                              hipStream_t stream) {
    const float* x = (const float*)d_in[0];        // [64,256,64,44]
    const float* lb = (const float*)d_in[1];       // [16,4,256]
    float* ws = (float*)d_ws;
    // ws (floats): pres 4096 | sup 720896 | pw 720896  (~5.8 MB)
    float* pres_ws = ws;
    float* sup_ws  = pres_ws + 4096;
    float* pw_ws   = sup_ws + 720896;

    float* out = (float*)d_out;
    float* tok  = out;                     // [64,256,64]
    float* pres = out + 1048576;           // [64,64]
    float* outS = out + 1052672;           // [64,2816,64]
    float* outP = outS + 11534336;         // [64,2816,64]

    routing_kernel<<<dim3(GG, NN), 512, 0, stream>>>(x, lb, sup_ws, pw_ws, pres_ws);
    tokscat_kernel<<<dim3(GG, NN), 512, 0, stream>>>(
        x, (const float4*)sup_ws, (const float4*)pw_ws, tok, (float4*)outS, (float4*)outP);
    presence_kernel<<<NN, 64, 0, stream>>>(pres_ws, pres);
}

// Round 6
// 342.267 us; speedup vs baseline: 1.0277x; 1.0277x over previous
//
#include <hip/hip_runtime.h>
#include <math.h>

// ---------------- problem constants ----------------
#define GG   16      // stripes
#define KK   4       // latents per stripe
#define NN   64      // batch
#define CC   256     // channels
#define SHH  4       // stripe height
#define WW   44      // width
#define PP   176     // pixels per stripe
#define HWSZ 2816    // 64*44
#define CHW  720896  // CC*HWSZ
#define TOPKK 22     // int(176*0.125)

// ---------------- DPP wave64 ops (VALU pipe) ----------------
template<int CTRL, int RMASK>
__device__ __forceinline__ float dpp0(float v) {
    return __int_as_float(__builtin_amdgcn_update_dpp(
        0, __float_as_int(v), CTRL, RMASK, 0xF, true));
}
__device__ __forceinline__ float nbrL(float v) { return dpp0<0x138, 0xF>(v); } // wave_shr1
__device__ __forceinline__ float nbrR(float v) { return dpp0<0x130, 0xF>(v); } // wave_shl1

// sum of all 64 lanes; result valid on lane 63 only
__device__ __forceinline__ float wave_sum63(float v) {
    v += dpp0<0x111, 0xF>(v);
    v += dpp0<0x112, 0xF>(v);
    v += dpp0<0x114, 0xF>(v);
    v += dpp0<0x118, 0xF>(v);
    v += dpp0<0x142, 0xA>(v);   // bcast15 into rows 1,3
    v += dpp0<0x143, 0xC>(v);   // bcast31 into rows 2,3
    return v;
}
__device__ __forceinline__ float bcast63(float v) {
    return __int_as_float(__builtin_amdgcn_readlane(__float_as_int(v), 63));
}
__device__ __forceinline__ float wave_sum_all(float v) { return bcast63(wave_sum63(v)); }

// max over 64 lanes, broadcast; requires true max >= 0 (zero-fill safe)
__device__ __forceinline__ float wave_max_nn(float v) {
    v = fmaxf(v, dpp0<0x111, 0xF>(v));
    v = fmaxf(v, dpp0<0x112, 0xF>(v));
    v = fmaxf(v, dpp0<0x114, 0xF>(v));
    v = fmaxf(v, dpp0<0x118, 0xF>(v));
    v = fmaxf(v, dpp0<0x142, 0xA>(v));
    v = fmaxf(v, dpp0<0x143, 0xC>(v));
    return bcast63(v);
}

// ---------------- routing kernel (basis-norm + scatter folded in) ----------------
// grid (GG, NN), 512 threads = 8 waves; wave w owns channels [w*32, w*32+32).
// Register 3x3 pooling via DPP, prefetch depth 2; one LDS cross-wave
// reduction; finalize + topk; direct scatter of sup/pw into full-res outputs.
__global__ __launch_bounds__(512, 8) void routing_kernel(
    const float* __restrict__ x, const float* __restrict__ lb_raw,
    float* __restrict__ pw_ws, float* __restrict__ pres_ws,
    float4* __restrict__ outS, float4* __restrict__ outP) {
    const int g = blockIdx.x;
    const int n = blockIdx.y;
    const int tid = threadIdx.x;
    const int w = __builtin_amdgcn_readfirstlane(tid >> 6);
    const int lane = tid & 63;
    const bool al = lane < WW;

    __shared__ float4 pd[8][PP];     // per-wave d partials; pd[0] -> sum
    __shared__ float2 pnf[8][PP];    // (nrm, fe) partials; pnf[0] -> sum
    __shared__ float4 lbn_lds[CC];   // [c] -> float4 over k, scaled by 1/9
    __shared__ float redA[4], redB[4], zred[4][4];
    float4* sup4 = pd[2];            // reused after reduction
    float4* pw4  = pd[4];

    // ---- basis norm: wave k (0..3) normalizes latent (g,k) into LDS ----
    if (w < 4) {
        const float* row = lb_raw + ((size_t)g * KK + w) * CC;
        float v0 = row[lane], v1 = row[lane + 64], v2 = row[lane + 128], v3 = row[lane + 192];
        float ss = v0 * v0 + v1 * v1 + v2 * v2 + v3 * v3;
        float tot = wave_sum_all(ss);
        float sc = (1.0f / 9.0f) / fmaxf(sqrtf(tot), 1e-12f);
        float* dst = (float*)lbn_lds;
        dst[lane * 4 + w]         = v0 * sc;
        dst[(lane + 64) * 4 + w]  = v1 * sc;
        dst[(lane + 128) * 4 + w] = v2 * sc;
        dst[(lane + 192) * 4 + w] = v3 * sc;
    }
    __syncthreads();

    const float* xb = x + (size_t)n * CHW + g * PP;
    const int c0 = w * 32;

    float4 dk[4];
    float nr[4] = {0, 0, 0, 0}, fe[4] = {0, 0, 0, 0};
    #pragma unroll
    for (int s = 0; s < 4; ++s) dk[s] = make_float4(0, 0, 0, 0);

    // prefetch depth 2: channels i (cur), i+1 (nx) in flight
    const float* xp = xb + (size_t)c0 * HWSZ + lane;
    float c0r = 0, c1r = 0, c2r = 0, c3r = 0;
    float n0r = 0, n1r = 0, n2r = 0, n3r = 0;
    if (al) {
        c0r = xp[0]; c1r = xp[44]; c2r = xp[88]; c3r = xp[132];
        n0r = xp[HWSZ]; n1r = xp[HWSZ + 44]; n2r = xp[HWSZ + 88]; n3r = xp[HWSZ + 132];
    }
    xp += 2 * HWSZ;
    #pragma unroll 1
    for (int i = 0; i < 32; ++i) {
        float f0 = 0, f1 = 0, f2 = 0, f3 = 0;
        if (i < 30 && al) { f0 = xp[0]; f1 = xp[44]; f2 = xp[88]; f3 = xp[132]; }
        xp += HWSZ;
        float4 lbv = lbn_lds[c0 + i];   // wave-uniform -> LDS broadcast
        fe[0] += c0r * c0r; fe[1] += c1r * c1r; fe[2] += c2r * c2r; fe[3] += c3r * c3r;
        float h0 = c0r + nbrL(c0r) + nbrR(c0r);
        float h1 = c1r + nbrL(c1r) + nbrR(c1r);
        float h2 = c2r + nbrL(c2r) + nbrR(c2r);
        float h3 = c3r + nbrL(c3r) + nbrR(c3r);
        // raw 3x3 sums (1/9 folded into lbv; nrm fixed via inv=72/sqrt)
        float p0 = h0 + h1;          // row -1 zero pad
        float p1 = p0 + h2;
        float t23 = h2 + h3;
        float p2 = h1 + t23;
        float p3 = t23;              // row 4 zero pad
        nr[0] += p0 * p0; nr[1] += p1 * p1; nr[2] += p2 * p2; nr[3] += p3 * p3;
        dk[0].x += p0 * lbv.x; dk[0].y += p0 * lbv.y; dk[0].z += p0 * lbv.z; dk[0].w += p0 * lbv.w;
        dk[1].x += p1 * lbv.x; dk[1].y += p1 * lbv.y; dk[1].z += p1 * lbv.z; dk[1].w += p1 * lbv.w;
        dk[2].x += p2 * lbv.x; dk[2].y += p2 * lbv.y; dk[2].z += p2 * lbv.z; dk[2].w += p2 * lbv.w;
        dk[3].x += p3 * lbv.x; dk[3].y += p3 * lbv.y; dk[3].z += p3 * lbv.z; dk[3].w += p3 * lbv.w;
        c0r = n0r; c1r = n1r; c2r = n2r; c3r = n3r;
        n0r = f0; n1r = f1; n2r = f2; n3r = f3;
    }
    if (al) {
        #pragma unroll
        for (int s = 0; s < 4; ++s) {
            pd[w][s * 44 + lane]  = dk[s];
            pnf[w][s * 44 + lane] = make_float2(nr[s], fe[s]);
        }
    }
    __syncthreads();

    // ---- cross-wave reduction into slot 0 ----
    if (tid < PP) {
        float4 a = pd[0][tid];
        #pragma unroll
        for (int ww = 1; ww < 8; ++ww) {
            float4 b = pd[ww][tid];
            a.x += b.x; a.y += b.y; a.z += b.z; a.w += b.w;
        }
        pd[0][tid] = a;
    } else if (tid >= 256 && tid < 256 + PP) {
        const int p = tid - 256;
        float2 a = pnf[0][p];
        #pragma unroll
        for (int ww = 1; ww < 8; ++ww) {
            float2 b = pnf[ww][p];
            a.x += b.x; a.y += b.y;
        }
        pnf[0][p] = a;
    }
    __syncthreads();

    // ---- finalize (8 waves redundant; waves 0..3 write) ----
    const int s4 = w & 3;
    const int pix = s4 * 44 + (al ? lane : 0);
    float4 dv = pd[0][pix];
    float2 nf = pnf[0][pix];
    float nrm = nf.x;
    float fev = nf.y * (1.0f / 256.0f);

    float fmw = wave_max_nn(al ? fev : 0.0f);
    if (w < 4 && lane == 0) redA[s4] = fmw;
    __syncthreads();
    float femax = fmaxf(fmaxf(redA[0], redA[1]), fmaxf(redA[2], redA[3]));
    float den = fmaxf(femax, 1e-6f);
    bool pa = al && ((fev / den) > 0.05f);
    unsigned long long bl = __ballot((int)pa);
    if (w < 4 && lane == 0) redB[s4] = (float)__popcll(bl);
    __syncthreads();
    float cnt = redB[0] + redB[1] + redB[2] + redB[3];
    float actv = pa ? 1.0f : 0.0f;
    if (cnt <= 0.0f) actv = (al && (fev > 0.0f)) ? 1.0f : 0.0f;

    float inv = 72.0f / fmaxf(sqrtf(nrm), 9e-12f);   // 8/TEMP on raw 3x3 sums
    float L0 = dv.x * inv, L1 = dv.y * inv, L2 = dv.z * inv, L3 = dv.w * inv;
    float mx = fmaxf(fmaxf(L0, L1), fmaxf(L2, L3));
    float e0 = expf(L0 - mx), e1 = expf(L1 - mx), e2 = expf(L2 - mx), e3 = expf(L3 - mx);
    float esum = e0 + e1 + e2 + e3;
    float sc = actv / esum;
    float s0 = e0 * sc, s1 = e1 * sc, s2 = e2 * sc, s3 = e3 * sc;

    float z0 = wave_sum63(s0), z1 = wave_sum63(s1), z2 = wave_sum63(s2), z3 = wave_sum63(s3);
    if (w < 4 && lane == 63) { zred[s4][0] = z0; zred[s4][1] = z1; zred[s4][2] = z2; zred[s4][3] = z3; }
    __syncthreads();
    float Z0 = zred[0][0] + zred[1][0] + zred[2][0] + zred[3][0];
    float Z1 = zred[0][1] + zred[1][1] + zred[2][1] + zred[3][1];
    float Z2 = zred[0][2] + zred[1][2] + zred[2][2] + zred[3][2];
    float Z3 = zred[0][3] + zred[1][3] + zred[2][3] + zred[3][3];
    float q0 = s0 / fmaxf(Z0, 1e-6f);
    float q1 = s1 / fmaxf(Z1, 1e-6f);
    float q2 = s2 / fmaxf(Z2, 1e-6f);
    float q3 = s3 / fmaxf(Z3, 1e-6f);

    if (w < 4 && al) {
        float4 sv = make_float4(s0, s1, s2, s3);
        float4 qv = make_float4(q0, q1, q2, q3);
        sup4[pix] = sv;
        pw4[pix]  = qv;
        ((float4*)pw_ws)[(size_t)(n * GG + g) * PP + pix] = qv;   // for token kernel
    }
    __syncthreads();

    // ---- top-22 presence: wave k (0..3); waves 4..7 go straight to scatter ----
    if (w < 4) {
        const float* supf = (const float*)sup4;
        const int k = w;
        float v0 = supf[lane * 4 + k];
        float v1 = supf[(lane + 64) * 4 + k];
        float v2 = (lane < PP - 128) ? supf[(lane + 128) * 4 + k] : -1e30f;
        float tks = 0.0f;
        for (int it = 0; it < TOPKK; ++it) {
            float lm = fmaxf(v0, fmaxf(v1, v2));
            float M = wave_max_nn(lm);
            tks += M;
            unsigned long long mk = __ballot((int)(lm == M));
            int src = __ffsll(mk) - 1;
            if (lane == src) {
                if (v0 == M)      v0 = -1e30f;
                else if (v1 == M) v1 = -1e30f;
                else              v2 = -1e30f;
            }
        }
        if (lane == 0) pres_ws[(size_t)n * 64 + g * KK + k] = tks * (1.0f / (float)TOPKK);
    }

    // ---- direct scatter: block owns output pixels [g*176, g*176+176) ----
    // (no barrier needed: sup4/pw4 final since the last __syncthreads)
    {
        const size_t obase = ((size_t)n * HWSZ + (size_t)g * PP) * 16;
        const float4 z = make_float4(0, 0, 0, 0);
        #pragma unroll 1
        for (int j = tid; j < PP * 16; j += 512) {
            const int px = j >> 4, q = j & 15;
            const bool hit = (q == g);
            outS[obase + j] = hit ? sup4[px] : z;
            outP[obase + j] = hit ? pw4[px]  : z;
        }
    }
}

// ---------------- token kernel (R4 shape: 4096 blocks, 4 waves) ----------------
// grid (GG*4, NN), 256 threads; wave handles 16 channels. x re-read L3-hot.
__global__ __launch_bounds__(256, 8) void token_kernel(
    const float* __restrict__ x, const float* __restrict__ pw_ws,
    float* __restrict__ tok_out) {
    const int g = blockIdx.x & 15;
    const int chunk = blockIdx.x >> 4;
    const int n = blockIdx.y;
    const int w = __builtin_amdgcn_readfirstlane(threadIdx.x >> 6);
    const int lane = threadIdx.x & 63;

    const float4* pwq = (const float4*)pw_ws + (size_t)(n * GG + g) * PP;
    float4 pwa = pwq[lane];
    float4 pwb = pwq[lane + 64];
    float4 pwc = (lane < 48) ? pwq[lane + 128] : make_float4(0, 0, 0, 0);

    const int cb = chunk * 64 + w * 16;
    const float* xp = x + (size_t)n * CHW + g * PP + (size_t)cb * HWSZ + lane;
    float* tokg = tok_out + (size_t)n * CC * 64 + g * KK + (size_t)cb * 64;

    float a0 = xp[0];
    float a1 = xp[64];
    float a2 = (lane < 48) ? xp[128] : 0.0f;
    xp += HWSZ;
    #pragma unroll 1
    for (int i = 0; i < 16; ++i) {
        float b0 = 0, b1 = 0, b2 = 0;
        if (i < 15) {
            b0 = xp[0]; b1 = xp[64];
            if (lane < 48) b2 = xp[128];
        }
        xp += HWSZ;
        float t0 = a0 * pwa.x + a1 * pwb.x + a2 * pwc.x;
        float t1 = a0 * pwa.y + a1 * pwb.y + a2 * pwc.y;
        float t2 = a0 * pwa.z + a1 * pwb.z + a2 * pwc.z;
        float t3 = a0 * pwa.w + a1 * pwb.w + a2 * pwc.w;
        t0 = wave_sum63(t0); t1 = wave_sum63(t1); t2 = wave_sum63(t2); t3 = wave_sum63(t3);
        if (lane == 63) {
            *(float4*)(tokg + (size_t)i * 64) = make_float4(t0, t1, t2, t3);
        }
        a0 = b0; a1 = b1; a2 = b2;
    }
}

// ---------------- presence normalization ----------------
__global__ __launch_bounds__(64) void presence_kernel(
    const float* __restrict__ pres_ws, float* __restrict__ outp) {
    const int n = blockIdx.x;
    const int lane = threadIdx.x;
    float v = pres_ws[(size_t)n * 64 + lane];
    float tot = wave_sum_all(v);
    outp[(size_t)n * 64 + lane] = v / fmaxf(tot, 1e-6f);
}

// ---------------- launch ----------------
extern "C" void kernel_launch(void* const* d_in, const int* in_sizes, int n_in,
                              void* d_out, int out_size, void* d_ws, size_t ws_size,
                              hipStream_t stream) {
    const float* x = (const float*)d_in[0];        // [64,256,64,44]
    const float* lb = (const float*)d_in[1];       // [16,4,256]
    float* ws = (float*)d_ws;
    // ws (floats): pres 4096 | pw 720896  (~2.9 MB)
    float* pres_ws = ws;
    float* pw_ws   = pres_ws + 4096;

    float* out = (float*)d_out;
    float* tok  = out;                     // [64,256,64]
    float* pres = out + 1048576;           // [64,64]
    float* outS = out + 1052672;           // [64,2816,64]
    float* outP = outS + 11534336;         // [64,2816,64]

    routing_kernel<<<dim3(GG, NN), 512, 0, stream>>>(
        x, lb, pw_ws, pres_ws, (float4*)outS, (float4*)outP);
    token_kernel<<<dim3(GG * 4, NN), 256, 0, stream>>>(x, pw_ws, tok);   // x L3-hot
    presence_kernel<<<NN, 64, 0, stream>>>(pres_ws, pres);
}